// Round 6
// baseline (553.556 us; speedup 1.0000x reference)
//
#include <hip/hip_runtime.h>
#include <hip/hip_bf16.h>

typedef unsigned int u32;
typedef float f32x4 __attribute__((ext_vector_type(4)));
typedef short s16x8 __attribute__((ext_vector_type(8)));

#define LDA 136  // padded LDS row stride (bf16 elems) for k1

// workspace layout (bytes)
#define WQT_OFF 0ULL
#define WKT_OFF 32768ULL
#define WVT_OFF 65536ULL
#define OPWT_OFF 98304ULL
#define Q_OFF 114688ULL
#define K_OFF (Q_OFF + 8388608ULL)
#define VT_OFF (K_OFF + 8388608ULL)
#define GATE_OFF (VT_OFF + 8388608ULL)
// total ws need = GATE_OFF + 16 MiB ~= 42 MiB

__device__ __forceinline__ u32 f2bf(float f) {  // RNE float->bf16 bits
  u32 u = __float_as_uint(f);
  return (u + 0x7fffu + ((u >> 16) & 1u)) >> 16;
}

__device__ __forceinline__ u32 pk2bf(float a, float b) {  // packed pair via v_cvt_pk_bf16_f32
  __hip_bfloat162 h = __float22bfloat162_rn(make_float2(a, b));
  u32 r;
  __builtin_memcpy(&r, &h, 4);
  return r;
}

__device__ __forceinline__ void gl_lds16(const void* g, void* l) {
  __builtin_amdgcn_global_load_lds((const __attribute__((address_space(1))) void*)g,
                                   (__attribute__((address_space(3))) void*)l, 16, 0, 0);
}

// ---- k0: transpose weights to bf16; fold a_w * (1/sqrt(128)) * log2(e) into Wk^T ----
__global__ void k0_wt(const float* Wq, const float* Wk, const float* Wv,
                      const float* aw, const float* opW, char* ws) {
  int nt = blockIdx.x, part = blockIdx.y;
  int kksh = (nt == 3) ? 6 : 7;
  int KK = 1 << kksh;
  const float* S = (nt == 0) ? Wq : (nt == 1) ? Wk : (nt == 2) ? Wv : opW;
  unsigned short* D = (unsigned short*)(ws + (nt == 0 ? WQT_OFF : nt == 1 ? WKT_OFF : nt == 2 ? WVT_OFF : OPWT_OFF));
  int base = part * 8 * KK;
  for (int i = threadIdx.x; i < 8 * KK; i += 256) {
    int d = part * 8 + (i >> kksh), k = i & (KK - 1);
    float v = S[k * 128 + d];
    if (nt == 1) v *= aw[d] * 0.12751743f;  // (1/sqrt(128)) * log2(e)
    D[base + i] = (unsigned short)f2bf(v);
  }
}

// ---- k1: Q = h@Wq (bf16 [e][d]), K = h@Wk_scaled ([e][d]), Vt = (h@Wv)^T ([d][e]),
// ----     gate = sigmoid(op_emb@opW + op_b) (fp32 [e][d]).
// ----     R5 post-mortem: mask architecture dead (producer >=100us standalone at 2.7 TB/s
// ----     vs 63us it saves in k2). adj stays inline in k2.
__launch_bounds__(256, 2)
__global__ void k1_proj(const float* __restrict__ h, const float* __restrict__ op_emb,
                        const float* __restrict__ op_b, char* __restrict__ ws) {
  int nt = blockIdx.x, et = blockIdx.y;
  int kksh = (nt == 3) ? 6 : 7;
  int KK = 1 << kksh;
  __shared__ unsigned short bufA[128 * LDA];
  __shared__ unsigned short bufB[128 * LDA];
  unsigned short* wbuf = (nt == 2) ? bufB : bufA;
  unsigned short* xbuf = (nt == 2) ? bufA : bufB;
  const unsigned short* Wt = (const unsigned short*)(ws + (nt == 0 ? WQT_OFF : nt == 1 ? WKT_OFF : nt == 2 ? WVT_OFF : OPWT_OFF));
  {
    const uint4* Ws = (const uint4*)Wt;
    int cnt = 128 * KK / 8;
    for (int i = threadIdx.x; i < cnt; i += 256) {
      uint4 v = Ws[i];
      int r = (8 * i) >> kksh, c = (8 * i) & (KK - 1);
      *(uint4*)&wbuf[r * LDA + c] = v;
    }
  }
  {
    const float* X = (nt == 3) ? (op_emb + (size_t)et * 128 * 64) : (h + (size_t)et * 128 * 128);
    int cnt = 128 * KK / 4;
    for (int i = threadIdx.x; i < cnt; i += 256) {
      float4 v = *(const float4*)(X + 4 * i);
      int r = (4 * i) >> kksh, c = (4 * i) & (KK - 1);
      *(uint2*)&xbuf[r * LDA + c] = make_uint2(pk2bf(v.x, v.y), pk2bf(v.z, v.w));
    }
  }
  __syncthreads();
  int tid = threadIdx.x, w = tid >> 6, lane = tid & 63, l15 = lane & 15, q = lane >> 4;
  int wa = w >> 1, wb = w & 1;
  f32x4 acc[4][4];
#pragma unroll
  for (int a = 0; a < 4; a++)
#pragma unroll
    for (int bq = 0; bq < 4; bq++) acc[a][bq] = f32x4{0.f, 0.f, 0.f, 0.f};
  for (int ks = 0; ks < KK / 32; ks++) {
    s16x8 af[4], bf_[4];
#pragma unroll
    for (int mt = 0; mt < 4; mt++)
      af[mt] = *(const s16x8*)&bufA[(wa * 64 + mt * 16 + l15) * LDA + ks * 32 + q * 8];
#pragma unroll
    for (int n2 = 0; n2 < 4; n2++)
      bf_[n2] = *(const s16x8*)&bufB[(wb * 64 + n2 * 16 + l15) * LDA + ks * 32 + q * 8];
#pragma unroll
    for (int mt = 0; mt < 4; mt++)
#pragma unroll
      for (int n2 = 0; n2 < 4; n2++)
        acc[mt][n2] = __builtin_amdgcn_mfma_f32_16x16x32_bf16(af[mt], bf_[n2], acc[mt][n2], 0, 0, 0);
  }
  if (nt <= 1) {
    unsigned short* Dst = (unsigned short*)(ws + (nt == 0 ? Q_OFF : K_OFF));
#pragma unroll
    for (int mt = 0; mt < 4; mt++)
#pragma unroll
      for (int n2 = 0; n2 < 4; n2++) {
        int d0 = wa * 64 + mt * 16 + q * 4;
        int eg = et * 128 + wb * 64 + n2 * 16 + l15;
        f32x4 a = acc[mt][n2];
        *(uint2*)(Dst + (size_t)eg * 128 + d0) = make_uint2(pk2bf(a[0], a[1]), pk2bf(a[2], a[3]));
      }
  } else if (nt == 2) {
    unsigned short* Dst = (unsigned short*)(ws + VT_OFF);
    int b = et >> 4;
    int ein0 = (et & 15) * 128;
#pragma unroll
    for (int mt = 0; mt < 4; mt++)
#pragma unroll
      for (int n2 = 0; n2 < 4; n2++) {
        int e0b = ein0 + wa * 64 + mt * 16 + q * 4;
        int d = wb * 64 + n2 * 16 + l15;
        f32x4 a = acc[mt][n2];
        *(uint2*)(Dst + (size_t)b * 128 * 2048 + (size_t)d * 2048 + e0b) =
            make_uint2(pk2bf(a[0], a[1]), pk2bf(a[2], a[3]));
      }
  } else {
    float* Dst = (float*)(ws + GATE_OFF);
#pragma unroll
    for (int mt = 0; mt < 4; mt++)
#pragma unroll
      for (int n2 = 0; n2 < 4; n2++) {
        int d0 = wa * 64 + mt * 16 + q * 4;
        int eg = et * 128 + wb * 64 + n2 * 16 + l15;
        f32x4 a = acc[mt][n2];
        float4 g4;
        g4.x = 1.f / (1.f + __builtin_amdgcn_exp2f(-(a[0] + op_b[d0 + 0]) * 1.4426950f));
        g4.y = 1.f / (1.f + __builtin_amdgcn_exp2f(-(a[1] + op_b[d0 + 1]) * 1.4426950f));
        g4.z = 1.f / (1.f + __builtin_amdgcn_exp2f(-(a[2] + op_b[d0 + 2]) * 1.4426950f));
        g4.w = 1.f / (1.f + __builtin_amdgcn_exp2f(-(a[3] + op_b[d0 + 3]) * 1.4426950f));
        *(float4*)(Dst + (size_t)eg * 128 + d0) = g4;
      }
  }
}

// ---- k2: fused attention + gate + LayerNorm, inline adj with DEEP prefetch.
// Counted-vmcnt ledger (issue order fixed by sched_barrier pins):
//   ... K(it)@postB(it-1), V(it)@postC(it-1), adj(it+1)@postC(it-1), K(it+1)@postB(it) ...
//   [A](it): vmcnt(16) -> adj(it)+K(it) done; V(it)+adj(it+1) STAY IN FLIGHT
//   [B](it): vmcnt(8)  -> V(it) done; adj(it+1) stays in flight (never force-drained)
//   [C](it): lgkmcnt(0) only
// adj cover = C(it-1) .. softmax(it+1) ~= 1.6 iterations. avA/avB double buffer with
// static parity (hand-unrolled x2 loop; rule #20: no runtime-indexed register arrays).
// Tail verified: body14 = A16/B8 (issues K15,V15, no adj), body15 = A8/B0 (no issues).

#define BAR_A16 do { asm volatile("s_waitcnt vmcnt(16) lgkmcnt(0)\n\ts_barrier" ::: "memory"); \
                     __builtin_amdgcn_sched_barrier(0); } while (0)
#define BAR_A8  do { asm volatile("s_waitcnt vmcnt(8) lgkmcnt(0)\n\ts_barrier" ::: "memory"); \
                     __builtin_amdgcn_sched_barrier(0); } while (0)
#define BAR_B8  do { asm volatile("s_waitcnt vmcnt(8) lgkmcnt(0)\n\ts_barrier" ::: "memory"); \
                     __builtin_amdgcn_sched_barrier(0); } while (0)
#define BAR_B0  do { asm volatile("s_waitcnt vmcnt(0) lgkmcnt(0)\n\ts_barrier" ::: "memory"); \
                     __builtin_amdgcn_sched_barrier(0); } while (0)
#define BAR_C   do { asm volatile("s_waitcnt lgkmcnt(0)\n\ts_barrier" ::: "memory"); \
                     __builtin_amdgcn_sched_barrier(0); } while (0)

#define ISSUE_K(ITP1) do { \
  const unsigned short* kb_ = Kg + (size_t)(ITP1) * 16384; \
  _Pragma("unroll") \
  for (int j_ = 0; j_ < 8; j_++) { \
    int S_ = (j_ * 4 + w) * 64 + lane; \
    int r_ = S_ >> 4, c_ = (S_ & 15) ^ (r_ & 15); \
    gl_lds16(kb_ + (size_t)r_ * 128 + (c_ << 3), Klds + (j_ * 4 + w) * 1024); \
  } \
  __builtin_amdgcn_sched_barrier(0); \
} while (0)

#define ISSUE_V(ITP1) do { \
  const unsigned short* vb_ = Vtg + (size_t)(ITP1) * 128; \
  _Pragma("unroll") \
  for (int j_ = 0; j_ < 8; j_++) { \
    int S_ = (j_ * 4 + w) * 64 + lane; \
    int r_ = S_ >> 4, c_ = (S_ & 15) ^ (r_ & 15); \
    gl_lds16(vb_ + (size_t)r_ * 2048 + (c_ << 3), Vlds + (j_ * 4 + w) * 1024); \
  } \
  __builtin_amdgcn_sched_barrier(0); \
} while (0)

#define ISSUE_ADJ(ITN, AV) do { \
  const float* ab_ = adjg + (size_t)(ITN) * 128; \
  _Pragma("unroll") \
  for (int et_ = 0; et_ < 2; et_++) { \
    const int e_ = we * 32 + et_ * 16 + l15; \
    _Pragma("unroll") \
    for (int lt_ = 0; lt_ < 4; lt_++) \
      AV[et_][lt_] = *(const float4*)(ab_ + (size_t)e_ * 2048 + wh * 64 + lt_ * 16 + q * 4); \
  } \
  __builtin_amdgcn_sched_barrier(0); \
} while (0)

#define K2_ITER(IT, AV, BARA, BARB, DO_ISS, DO_ADJ2) do { \
  BARA; /* K(IT)+adj(IT) resident; V(IT)(+adj(IT+1)) in flight */ \
  f32x4 sacc[4][2]; \
  _Pragma("unroll") \
  for (int lt = 0; lt < 4; lt++) \
    _Pragma("unroll") \
    for (int et = 0; et < 2; et++) sacc[lt][et] = f32x4{0.f, 0.f, 0.f, 0.f}; \
  _Pragma("unroll") \
  for (int ks = 0; ks < 4; ks++) { \
    s16x8 kf[4]; \
    _Pragma("unroll") \
    for (int lt = 0; lt < 4; lt++) { \
      int l = wh * 64 + lt * 16 + l15; \
      kf[lt] = *(const s16x8*)(Klds + l * 256 + (((ks * 4 + q) ^ l15) << 4)); \
    } \
    _Pragma("unroll") \
    for (int lt = 0; lt < 4; lt++) \
      _Pragma("unroll") \
      for (int et = 0; et < 2; et++) \
        sacc[lt][et] = __builtin_amdgcn_mfma_f32_16x16x32_bf16(kf[lt], qf[et][ks], sacc[lt][et], 0, 0, 0); \
  } \
  _Pragma("unroll") \
  for (int et = 0; et < 2; et++) { \
    const int e = we * 32 + et * 16 + l15; \
    float dsum = 0.0f; \
    _Pragma("unroll") \
    for (int lt = 0; lt < 4; lt++) { \
      float4 aj = AV[et][lt]; \
      f32x4 s = sacc[lt][et]; \
      float p0 = __builtin_amdgcn_exp2f(fmaxf(s[0], 0.2f * s[0]) * aj.x); \
      float p1 = __builtin_amdgcn_exp2f(fmaxf(s[1], 0.2f * s[1]) * aj.y); \
      float p2 = __builtin_amdgcn_exp2f(fmaxf(s[2], 0.2f * s[2]) * aj.z); \
      float p3 = __builtin_amdgcn_exp2f(fmaxf(s[3], 0.2f * s[3]) * aj.w); \
      dsum += (p0 + p1) + (p2 + p3); \
      int chunk = wh * 8 + lt * 2 + (q >> 1); \
      *(uint2*)(PL + e * 256 + ((chunk ^ l15) << 4) + (q & 1) * 8) = \
          make_uint2(pk2bf(p0, p1), pk2bf(p2, p3)); \
    } \
    if (et == 0) dp0 += dsum; else dp1 += dsum; \
  } \
  BARB; /* V(IT) resident; PL ready; Klds free; adj(IT+1) still flying */ \
  if (DO_ISS) ISSUE_K((IT) + 1); \
  _Pragma("unroll") \
  for (int ks = 0; ks < 4; ks++) { \
    s16x8 af[2], vf[4]; \
    _Pragma("unroll") \
    for (int et = 0; et < 2; et++) { \
      const int e = we * 32 + et * 16 + l15; \
      af[et] = *(const s16x8*)(PL + e * 256 + (((ks * 4 + q) ^ l15) << 4)); \
    } \
    _Pragma("unroll") \
    for (int dt = 0; dt < 4; dt++) { \
      int d = wh * 64 + dt * 16 + l15; \
      vf[dt] = *(const s16x8*)(Vlds + d * 256 + (((ks * 4 + q) ^ l15) << 4)); \
    } \
    _Pragma("unroll") \
    for (int et = 0; et < 2; et++) \
      _Pragma("unroll") \
      for (int dt = 0; dt < 4; dt++) \
        oacc[et][dt] = __builtin_amdgcn_mfma_f32_16x16x32_bf16(af[et], vf[dt], oacc[et][dt], 0, 0, 0); \
  } \
  BAR_C; /* Vlds free; K(IT+1)(+adj) stay in flight */ \
  if (DO_ISS) { \
    ISSUE_V((IT) + 1); \
    if (DO_ADJ2) ISSUE_ADJ((IT) + 2, AV); \
  } \
} while (0)

__launch_bounds__(256, 2)
__global__ void k2_attn(const float* __restrict__ adj, const float* __restrict__ ln_g,
                        const float* __restrict__ ln_b, char* __restrict__ ws,
                        float* __restrict__ out) {
  __shared__ char smem[81920];
  char* Klds = smem;           // K tile [l=128][k=128] bf16, rows 256 B
  char* Vlds = smem + 32768;   // Vt tile [d=128][l=128] bf16, rows 256 B
  char* PL = smem + 65536;     // P [e=64][l=128] bf16, rows 256 B (shared across waves)

  const int bid = blockIdx.x;
  const int xcd = bid & 7, slot = bid >> 3;
  const int b = xcd * 2 + (slot >> 5);  // 2 batches per XCD: K/Vt stay L2-resident
  const int e0 = (slot & 31) << 6;

  const unsigned short* Qg = (const unsigned short*)(ws + Q_OFF) + ((size_t)b * 2048 + e0) * 128;
  const unsigned short* Kg = (const unsigned short*)(ws + K_OFF) + (size_t)b * 2048 * 128;
  const unsigned short* Vtg = (const unsigned short*)(ws + VT_OFF) + (size_t)b * 128 * 2048;
  const float* gateg = (const float*)(ws + GATE_OFF) + ((size_t)b * 2048 + e0) * 128;
  const float* adjg = adj + (size_t)b * 2048 * 2048 + (size_t)e0 * 2048;

  const int tid = threadIdx.x;
  const int w = tid >> 6, lane = tid & 63, l15 = lane & 15, q = lane >> 4;
  const int wh = w >> 1, we = w & 1;  // wh: l-half (GEMM1) / d-half (GEMM2); we: e-half

  // persistent Q B-frags: B[k=proj][n=e]
  s16x8 qf[2][4];
#pragma unroll
  for (int et = 0; et < 2; et++) {
    const int e = we * 32 + et * 16 + l15;
#pragma unroll
    for (int ks = 0; ks < 4; ks++)
      qf[et][ks] = *(const s16x8*)(Qg + (size_t)e * 128 + ks * 32 + q * 8);
  }
  asm volatile("s_waitcnt vmcnt(0)" ::: "memory");  // Q regs settled before ledger starts
  __builtin_amdgcn_sched_barrier(0);

  // O accumulators + denominator partials
  f32x4 oacc[2][4];
#pragma unroll
  for (int et = 0; et < 2; et++)
#pragma unroll
    for (int dt = 0; dt < 4; dt++) oacc[et][dt] = f32x4{0.f, 0.f, 0.f, 0.f};
  float dp0 = 0.0f, dp1 = 0.0f;
  float4 avA[2][4], avB[2][4];  // adj double buffer: even iters consume/refill avA, odd avB

  // prolog ledger (order pinned): adj(0)->avA, K(0), V(0), adj(1)->avB  = 32 ops
  // BAR_A16 at it=0: oldest 16 = adj(0)+K(0) done; V(0)+adj(1) fly. Steady from start.
  ISSUE_ADJ(0, avA);
  ISSUE_K(0);
  ISSUE_V(0);
  ISSUE_ADJ(1, avB);

#pragma unroll 1
  for (int it2 = 0; it2 < 7; it2++) {
    const int itE = it2 * 2;
    K2_ITER(itE, avA, BAR_A16, BAR_B8, true, true);
    K2_ITER(itE + 1, avB, BAR_A16, BAR_B8, true, true);
  }
  K2_ITER(14, avA, BAR_A16, BAR_B8, true, false);  // issues K(15),V(15); no adj(16)
  K2_ITER(15, avB, BAR_A8, BAR_B0, false, false);  // drains everything; final BAR_C

  // ---- epilogue ----
  // sden overlays the now-dead PL region (LDS total stays 81920 -> 2 blocks/CU)
  float* sden = (float*)(smem + 65536);
  if (tid < 64) sden[tid] = 0.0f;
  __syncthreads();  // sden zeroed (also: all PL reads done before overlay write)
  atomicAdd(&sden[we * 32 + l15], dp0);        // 8 contributors per e (2 wh x 4 q)
  atomicAdd(&sden[we * 32 + 16 + l15], dp1);

  // O2 [e=64][d=128] fp32 stride 132 overlays dead K/V tiles (33.8 KB)
  float* O2 = (float*)smem;
#pragma unroll
  for (int et = 0; et < 2; et++)
#pragma unroll
    for (int dt = 0; dt < 4; dt++) {
      const int eb = we * 32 + et * 16 + q * 4;
      const int d = wh * 64 + dt * 16 + l15;
      f32x4 v = oacc[et][dt];
#pragma unroll
      for (int r = 0; r < 4; r++) O2[(eb + r) * 132 + d] = v[r];
    }
  __syncthreads();  // O2 + sden visible

  // hp = gate * (O/den); LayerNorm; store. 4 threads per token, 32 features each.
  {
    const int e = tid >> 2, j = tid & 3;
    const float inv = 1.0f / sden[e];
    const float* row = O2 + e * 132 + j * 32;
    const float* gr = gateg + (size_t)e * 128 + j * 32;
    float4 x[8];
    float s1 = 0.f, s2 = 0.f;
#pragma unroll
    for (int i = 0; i < 8; i++) {
      float4 v = *(const float4*)(row + i * 4);
      float4 g = *(const float4*)(gr + i * 4);
      float4 hp;
      hp.x = v.x * inv * g.x; hp.y = v.y * inv * g.y;
      hp.z = v.z * inv * g.z; hp.w = v.w * inv * g.w;
      x[i] = hp;
      s1 += (hp.x + hp.y) + (hp.z + hp.w);
      s2 += (hp.x * hp.x + hp.y * hp.y) + (hp.z * hp.z + hp.w * hp.w);
    }
    s1 += __shfl_xor(s1, 1); s2 += __shfl_xor(s2, 1);
    s1 += __shfl_xor(s1, 2); s2 += __shfl_xor(s2, 2);
    const float mu = s1 * 0.0078125f;
    const float var = s2 * 0.0078125f - mu * mu;
    const float rs = rsqrtf(var + 1e-5f);
    float* orow = out + ((size_t)b * 2048 + e0 + e) * 128 + j * 32;
    const float* gg = ln_g + j * 32;
    const float* bb = ln_b + j * 32;
#pragma unroll
    for (int i = 0; i < 8; i++) {
      float4 gv = *(const float4*)(gg + i * 4);
      float4 bv = *(const float4*)(bb + i * 4);
      float4 o;
      o.x = (x[i].x - mu) * rs * gv.x + bv.x;
      o.y = (x[i].y - mu) * rs * gv.y + bv.y;
      o.z = (x[i].z - mu) * rs * gv.z + bv.z;
      o.w = (x[i].w - mu) * rs * gv.w + bv.w;
      *(float4*)(orow + i * 4) = o;
    }
  }
}

extern "C" void kernel_launch(void* const* d_in, const int* in_sizes, int n_in,
                              void* d_out, int out_size, void* d_ws, size_t ws_size,
                              hipStream_t stream) {
  const float* h = (const float*)d_in[0];
  const float* adj = (const float*)d_in[1];
  const float* op_emb = (const float*)d_in[2];
  const float* Wk = (const float*)d_in[3];
  const float* Wq = (const float*)d_in[4];
  const float* Wv = (const float*)d_in[5];
  const float* a_w = (const float*)d_in[6];
  const float* op_W = (const float*)d_in[7];
  const float* op_b = (const float*)d_in[8];
  const float* ln_g = (const float*)d_in[9];
  const float* ln_b = (const float*)d_in[10];
  char* ws = (char*)d_ws;
  float* out = (float*)d_out;

  k0_wt<<<dim3(4, 16), 256, 0, stream>>>(Wq, Wk, Wv, a_w, op_W, ws);
  k1_proj<<<dim3(4, 256), 256, 0, stream>>>(h, op_emb, op_b, ws);
  k2_attn<<<512, 256, 0, stream>>>(adj, ln_g, ln_b, ws, out);
}